// Round 1
// baseline (396.164 us; speedup 1.0000x reference)
//
#include <hip/hip_runtime.h>

typedef __attribute__((ext_vector_type(8))) short short8;
typedef __attribute__((ext_vector_type(4))) float f32x4;
typedef __attribute__((ext_vector_type(16))) float f32x16;

#define DEVFN __device__ __forceinline__

DEVFN unsigned short f2bf(float f) {
  unsigned int u = __builtin_bit_cast(unsigned int, f);
  u += 0x7FFFu + ((u >> 16) & 1u);   // RNE
  return (unsigned short)(u >> 16);
}
DEVFN float bf2f(unsigned int u) { return __builtin_bit_cast(float, u << 16); }

// ---------------- prep kernels ----------------

// cos/sin tables: [2048 pos][32 freq]
__global__ __launch_bounds__(256) void mk_tables(float* __restrict__ cost, float* __restrict__ sint) {
  int gid = blockIdx.x * 256 + threadIdx.x;   // 65536
  int pos = gid >> 5, i = gid & 31;
  float theta = powf(10000.0f, -(float)(2 * i) / 64.0f);
  float ang = (float)pos * theta;
  cost[gid] = cosf(ang);
  sint[gid] = sinf(ang);
}

__global__ __launch_bounds__(256) void bias_cat_k(const float* __restrict__ bq, const float* __restrict__ bk,
                                                  const float* __restrict__ bv, float* __restrict__ out) {
  int i = blockIdx.x * 256 + threadIdx.x;  // 3072
  float v;
  if (i < 2048) v = bq[i];
  else if (i < 2560) v = bk[i - 2048];
  else v = bv[i - 2560];
  out[i] = v;
}

__global__ __launch_bounds__(256) void convx(const float* __restrict__ x, unsigned short* __restrict__ xb) {
  int gid = blockIdx.x * 256 + threadIdx.x;   // 1048576 threads, 8 f32 each
  const float4* xv = (const float4*)x;
  float4 a = xv[(size_t)gid * 2], b = xv[(size_t)gid * 2 + 1];
  short8 u;
  u[0] = (short)f2bf(a.x); u[1] = (short)f2bf(a.y); u[2] = (short)f2bf(a.z); u[3] = (short)f2bf(a.w);
  u[4] = (short)f2bf(b.x); u[5] = (short)f2bf(b.y); u[6] = (short)f2bf(b.z); u[7] = (short)f2bf(b.w);
  *(short8*)(xb + (size_t)gid * 8) = u;
}

// W [2048][ncols] f32 -> Wt [ncols][2048] bf16 (Wt pre-offset by caller)
__global__ __launch_bounds__(256) void transw(const float* __restrict__ W, unsigned short* __restrict__ Wt, int ncols) {
  __shared__ float lds[32][33];
  int n0 = blockIdx.x * 32, k0 = blockIdx.y * 32;
  int tx = threadIdx.x & 31, ty = threadIdx.x >> 5;
  #pragma unroll
  for (int i = 0; i < 4; i++) {
    int kr = ty + i * 8;
    lds[kr][tx] = W[(size_t)(k0 + kr) * ncols + n0 + tx];
  }
  __syncthreads();
  #pragma unroll
  for (int i = 0; i < 4; i++) {
    int nr = ty + i * 8;
    Wt[(size_t)(n0 + nr) * 2048 + k0 + tx] = f2bf(lds[tx][nr]);
  }
}

// ---------------- RoPE + scatter ----------------
// QKV bf16 [4096][3072]; dst [B][NH][2048][128] bf16; one thread per (m,h,pair j)
template<int NH>
__global__ __launch_bounds__(256) void rope_scatter(const unsigned short* __restrict__ QKV,
    const float* __restrict__ cost, const float* __restrict__ sint, const int* __restrict__ spp,
    unsigned short* __restrict__ dst, int colOff, float scale) {
  constexpr int LOG2NH = (NH == 16) ? 4 : 2;
  int gid = blockIdx.x * 256 + threadIdx.x;
  int j = gid & 63;
  int h = (gid >> 6) & (NH - 1);
  int m = gid >> (6 + LOG2NH);
  int t = m & 2047;
  const unsigned short* src = QKV + (size_t)m * 3072 + colOff + h * 128 + 2 * j;
  unsigned int pair = *(const unsigned int*)src;
  float xv = bf2f(pair & 0xFFFFu), yv = bf2f(pair >> 16);
  float rx, ry;
  if (j < 32) {
    int pos = (spp[0] + t) & 2047;
    float c = cost[pos * 32 + j], s = sint[pos * 32 + j];
    rx = xv * c - yv * s;
    ry = xv * s + yv * c;
  } else { rx = xv; ry = yv; }
  rx *= scale; ry *= scale;
  size_t drow = ((size_t)((m >> 11) * NH + h)) * 2048 + t;
  unsigned int outp = (unsigned int)f2bf(rx) | ((unsigned int)f2bf(ry) << 16);
  *(unsigned int*)(dst + drow * 128 + 2 * j) = outp;
}

// ---------------- V transpose: QKV[.,2560+kh*128+d] -> Vt[b][kh][d][t] ----------------
__global__ __launch_bounds__(256) void vtrans(const unsigned short* __restrict__ QKV, unsigned short* __restrict__ Vt) {
  __shared__ __align__(16) unsigned short lds[64 * 128];  // swizzled [t][d]
  int tid = threadIdx.x;
  int t0 = blockIdx.x * 64;
  int bk = blockIdx.y;         // b*4 + kh
  const unsigned short* src = QKV + (size_t)(bk >> 2) * 2048 * 3072 + 2560 + (bk & 3) * 128;
  #pragma unroll
  for (int c = 0; c < 4; c++) {
    int idx = c * 256 + tid;
    int tr = idx >> 4, dc = idx & 15;
    short8 v = *(const short8*)(src + (size_t)(t0 + tr) * 3072 + dc * 8);
    *(short8*)((char*)lds + tr * 256 + 16 * (dc ^ (tr >> 3))) = v;
  }
  __syncthreads();
  unsigned short* dstb = Vt + (size_t)bk * 128 * 2048;
  #pragma unroll
  for (int c2 = 0; c2 < 4; c2++) {
    int idx2 = c2 * 256 + tid;
    int tc = idx2 & 7, d = idx2 >> 3;
    short8 u;
    #pragma unroll
    for (int e = 0; e < 8; e++) {
      int t = 8 * tc + e;
      u[e] = *(const short*)((char*)lds + t * 256 + 16 * ((d >> 3) ^ tc) + (d & 7) * 2);
    }
    *(short8*)(dstb + (size_t)d * 2048 + t0 + 8 * tc) = u;
  }
}

// ---------------- GEMM: C[M][N] = A[M][K] * Bt[N][K]^T + bias, m97 structure ----------------
template<bool BF16OUT>
__global__ __launch_bounds__(256, 2) void gemm_bt(
    const unsigned short* __restrict__ A, const unsigned short* __restrict__ Bt,
    const float* __restrict__ bias, void* __restrict__ Cout, int M, int N, int K) {
  __shared__ __align__(16) unsigned short Asl[128 * 64];
  __shared__ __align__(16) unsigned short Bsl[128 * 64];
  int tid = threadIdx.x;
  int lane = tid & 63, w = tid >> 6;
  int wr = w >> 1, wc = w & 1;
  int m0 = blockIdx.y * 128, n0 = blockIdx.x * 128;

  f32x4 acc[4][4];
  #pragma unroll
  for (int i = 0; i < 4; i++)
    #pragma unroll
    for (int j = 0; j < 4; j++)
      #pragma unroll
      for (int r = 0; r < 4; r++) acc[i][j][r] = 0.f;

  int srow = w * 32 + (lane >> 3);        // rows for this wave's 4 staging chunks (i*8 apart)
  int kc8 = (lane & 7) * 8;
  const unsigned short* Aptr = A + (size_t)(m0 + srow) * K + kc8;
  const unsigned short* Bptr = Bt + (size_t)(n0 + srow) * K + kc8;
  unsigned short* AslW = Asl + w * 4 * 512;
  unsigned short* BslW = Bsl + w * 4 * 512;

  for (int k0 = 0; k0 < K; k0 += 64) {
    __syncthreads();
    #pragma unroll
    for (int i = 0; i < 4; i++) {
      __builtin_amdgcn_global_load_lds(
        (const __attribute__((address_space(1))) unsigned int*)(Aptr + (size_t)i * 8 * K + k0),
        (__attribute__((address_space(3))) unsigned int*)(AslW + i * 512), 16, 0, 0);
      __builtin_amdgcn_global_load_lds(
        (const __attribute__((address_space(1))) unsigned int*)(Bptr + (size_t)i * 8 * K + k0),
        (__attribute__((address_space(3))) unsigned int*)(BslW + i * 512), 16, 0, 0);
    }
    __syncthreads();
    #pragma unroll
    for (int ks = 0; ks < 2; ks++) {
      short8 af[4], bfr[4];
      #pragma unroll
      for (int mi = 0; mi < 4; mi++)
        af[mi] = *(const short8*)(Asl + (wr * 64 + mi * 16 + (lane & 15)) * 64 + ks * 32 + (lane >> 4) * 8);
      #pragma unroll
      for (int ni = 0; ni < 4; ni++)
        bfr[ni] = *(const short8*)(Bsl + (wc * 64 + ni * 16 + (lane & 15)) * 64 + ks * 32 + (lane >> 4) * 8);
      #pragma unroll
      for (int mi = 0; mi < 4; mi++)
        #pragma unroll
        for (int ni = 0; ni < 4; ni++)
          acc[mi][ni] = __builtin_amdgcn_mfma_f32_16x16x32_bf16(af[mi], bfr[ni], acc[mi][ni], 0, 0, 0);
    }
  }
  int cl = lane & 15, rq = lane >> 4;
  #pragma unroll
  for (int mi = 0; mi < 4; mi++) {
    #pragma unroll
    for (int ni = 0; ni < 4; ni++) {
      int gn = n0 + wc * 64 + ni * 16 + cl;
      float bv = bias[gn];
      #pragma unroll
      for (int r = 0; r < 4; r++) {
        int gm = m0 + wr * 64 + mi * 16 + rq * 4 + r;
        float v = acc[mi][ni][r] + bv;
        if (BF16OUT) ((unsigned short*)Cout)[(size_t)gm * N + gn] = f2bf(v);
        else ((float*)Cout)[(size_t)gm * N + gn] = v;
      }
    }
  }
}

// ---------------- flash attention ----------------
// Qr [B][16][T][128] (pre-scaled by 1/sqrt(128)), Kr [B][4][T][128], Vt [B][4][128][T]
// grid: (T/128, B*16); 4 waves, 32 q-rows per wave, KV tile = 64
__global__ __launch_bounds__(256, 2) void attn_kernel(
    const unsigned short* __restrict__ Qr, const unsigned short* __restrict__ Kr,
    const unsigned short* __restrict__ Vt, unsigned short* __restrict__ O) {
  __shared__ __align__(16) unsigned short K_lds[64 * 136];   // [kv][128 + 8 pad]
  __shared__ __align__(16) unsigned short V_lds[128 * 72];   // [d][64 + 8 pad]
  __shared__ __align__(16) unsigned short P_lds[4 * 32 * 72];// per-wave [32 q][64 + 8 pad]

  const int tid = threadIdx.x;
  const int lane = tid & 63;
  const int w = tid >> 6;
  const int l31 = lane & 31;
  const int lhalf = lane >> 5;
  const int q0 = blockIdx.x * 128;
  const int bh = blockIdx.y;
  const int b = bh >> 4, h = bh & 15;
  const int kh = h >> 2;

  // Q fragments for this wave's 32 rows (A-frag: row=l&31, k=8*(l>>5)+e per 16-k slice)
  const unsigned short* qbase = Qr + (((size_t)(b * 16 + h)) * 2048 + (q0 + w * 32 + l31)) * 128;
  short8 qf[8];
  #pragma unroll
  for (int s = 0; s < 8; s++)
    qf[s] = *(const short8*)(qbase + s * 16 + lhalf * 8);

  float m_r[16], l_r[16];
  f32x16 oacc[4];
  #pragma unroll
  for (int r = 0; r < 16; r++) { m_r[r] = -3.0e38f; l_r[r] = 0.f; }
  #pragma unroll
  for (int dt = 0; dt < 4; dt++)
    #pragma unroll
    for (int r = 0; r < 16; r++) oacc[dt][r] = 0.f;

  const unsigned short* kbase = Kr + ((size_t)(b * 4 + kh)) * 2048 * 128;
  const unsigned short* vbase = Vt + ((size_t)(b * 4 + kh)) * 128 * 2048;
  unsigned short* Pw = P_lds + w * 32 * 72;

  const int ntiles = q0 / 64 + 2;
  for (int kt = 0; kt < ntiles; kt++) {
    const int kv0 = kt * 64;
    __syncthreads();
    #pragma unroll
    for (int c = 0; c < 4; c++) {      // stage K: 64x128
      int idx = c * 256 + tid;
      int kvr = idx >> 4, dc = idx & 15;
      short8 v = *(const short8*)(kbase + (size_t)(kv0 + kvr) * 128 + dc * 8);
      *(short8*)((char*)K_lds + kvr * 272 + dc * 16) = v;
    }
    #pragma unroll
    for (int c = 0; c < 4; c++) {      // stage V^T: 128x64
      int idx = c * 256 + tid;
      int d = idx >> 3, kvc = idx & 7;
      short8 v = *(const short8*)(vbase + (size_t)d * 2048 + kv0 + kvc * 8);
      *(short8*)((char*)V_lds + d * 144 + kvc * 16) = v;
    }
    __syncthreads();

    const int qmin_w = q0 + w * 32;
    if (kv0 <= qmin_w + 31) {          // wave has at least one unmasked row
      // QK^T: scores 32q x 64kv as two 32x32 tiles
      f32x16 sc[2];
      #pragma unroll
      for (int ct = 0; ct < 2; ct++) {
        #pragma unroll
        for (int r = 0; r < 16; r++) sc[ct][r] = 0.f;
        #pragma unroll
        for (int s = 0; s < 8; s++) {
          short8 kf = *(const short8*)((char*)K_lds + (ct * 32 + l31) * 272 + s * 32 + lhalf * 16);
          sc[ct] = __builtin_amdgcn_mfma_f32_32x32x16_bf16(qf[s], kf, sc[ct], 0, 0, 0);
        }
      }
      if (kv0 + 63 > qmin_w) {         // causal mask needed
        #pragma unroll
        for (int ct = 0; ct < 2; ct++)
          #pragma unroll
          for (int r = 0; r < 16; r++) {
            int qg = qmin_w + (r & 3) + 8 * (r >> 2) + 4 * lhalf;
            int kg = kv0 + ct * 32 + l31;
            if (kg > qg) sc[ct][r] = -3.0e38f;
          }
      }
      // online softmax (rows spread over regs; cols over 32 lanes of each half)
      #pragma unroll
      for (int r = 0; r < 16; r++) {
        float s0 = sc[0][r], s1 = sc[1][r];
        float tm = fmaxf(s0, s1);
        tm = fmaxf(tm, __shfl_xor(tm, 1));
        tm = fmaxf(tm, __shfl_xor(tm, 2));
        tm = fmaxf(tm, __shfl_xor(tm, 4));
        tm = fmaxf(tm, __shfl_xor(tm, 8));
        tm = fmaxf(tm, __shfl_xor(tm, 16));
        float mn = fmaxf(m_r[r], tm);
        float al = __expf(m_r[r] - mn);
        float p0 = __expf(s0 - mn);
        float p1 = __expf(s1 - mn);
        float rs = p0 + p1;
        rs += __shfl_xor(rs, 1);
        rs += __shfl_xor(rs, 2);
        rs += __shfl_xor(rs, 4);
        rs += __shfl_xor(rs, 8);
        rs += __shfl_xor(rs, 16);
        m_r[r] = mn;
        l_r[r] = l_r[r] * al + rs;
        #pragma unroll
        for (int dt = 0; dt < 4; dt++) oacc[dt][r] *= al;
        int row16 = (r & 3) + 8 * (r >> 2) + 4 * lhalf;
        Pw[row16 * 72 + l31] = f2bf(p0);
        Pw[row16 * 72 + 32 + l31] = f2bf(p1);
      }
      // PV: O[32q x 128d] += P[32x64] * V[64x128]
      short8 pf[4];
      #pragma unroll
      for (int s = 0; s < 4; s++)
        pf[s] = *(const short8*)((char*)Pw + l31 * 144 + s * 32 + lhalf * 16);
      #pragma unroll
      for (int dt = 0; dt < 4; dt++) {
        #pragma unroll
        for (int s = 0; s < 4; s++) {
          short8 vf = *(const short8*)((char*)V_lds + (dt * 32 + l31) * 144 + s * 32 + lhalf * 16);
          oacc[dt] = __builtin_amdgcn_mfma_f32_32x32x16_bf16(pf[s], vf, oacc[dt], 0, 0, 0);
        }
      }
    }
  }
  // epilogue: O[b][q][h*128 + d] bf16
  #pragma unroll
  for (int r = 0; r < 16; r++) {
    float inv = 1.0f / l_r[r];
    int qg = q0 + w * 32 + (r & 3) + 8 * (r >> 2) + 4 * lhalf;
    unsigned short* orow = O + ((size_t)(b * 2048 + qg)) * 2048 + h * 128;
    #pragma unroll
    for (int dt = 0; dt < 4; dt++)
      orow[dt * 32 + l31] = f2bf(oacc[dt][r] * inv);
  }
}

// ---------------- launch ----------------
extern "C" void kernel_launch(void* const* d_in, const int* in_sizes, int n_in,
                              void* d_out, int out_size, void* d_ws, size_t ws_size,
                              hipStream_t stream) {
  (void)in_sizes; (void)n_in; (void)out_size; (void)ws_size;
  const float* x  = (const float*)d_in[0];
  const float* Wq = (const float*)d_in[1];
  const float* bq = (const float*)d_in[2];
  const float* Wk = (const float*)d_in[3];
  const float* bk = (const float*)d_in[4];
  const float* Wv = (const float*)d_in[5];
  const float* bv = (const float*)d_in[6];
  const float* Wo = (const float*)d_in[7];
  const float* bo = (const float*)d_in[8];
  const int*   sp = (const int*)d_in[9];

  char* ws = (char*)d_ws;
  unsigned short* xb    = (unsigned short*)ws;                // 16,777,216 B (reused as Obuf)
  unsigned short* Wqkvt = (unsigned short*)(ws + 16777216);   // 12,582,912
  unsigned short* Wot   = (unsigned short*)(ws + 29360128);   //  8,388,608
  unsigned short* QKVb  = (unsigned short*)(ws + 37748736);   // 25,165,824 (bf16 [4096][3072])
  float* cost           = (float*)(ws + 62914560);            //    262,144
  float* sint           = (float*)(ws + 63176704);            //    262,144
  float* bcat           = (float*)(ws + 63438848);            //     12,288  -> total 63,451,136 B

  unsigned short* Obuf = xb;  // xb dead after GEMM1
  // Qr/Kr/Vt live in d_out (32 MB), fully dead before final GEMM writes d_out
  unsigned short* Qr = (unsigned short*)d_out;
  unsigned short* Kr = (unsigned short*)((char*)d_out + 16777216);
  unsigned short* Vtb = (unsigned short*)((char*)d_out + 20971520);

  mk_tables<<<256, 256, 0, stream>>>(cost, sint);
  bias_cat_k<<<12, 256, 0, stream>>>(bq, bk, bv, bcat);
  convx<<<4096, 256, 0, stream>>>(x, xb);
  transw<<<dim3(64, 64), 256, 0, stream>>>(Wq, Wqkvt, 2048);
  transw<<<dim3(16, 64), 256, 0, stream>>>(Wk, Wqkvt + (size_t)2048 * 2048, 512);
  transw<<<dim3(16, 64), 256, 0, stream>>>(Wv, Wqkvt + (size_t)2560 * 2048, 512);
  transw<<<dim3(64, 64), 256, 0, stream>>>(Wo, Wot, 2048);
  gemm_bt<true><<<dim3(24, 32), 256, 0, stream>>>(xb, Wqkvt, bcat, QKVb, 4096, 3072, 2048);
  rope_scatter<16><<<16384, 256, 0, stream>>>(QKVb, cost, sint, sp, Qr, 0, 0.08838834764831845f);
  rope_scatter<4><<<4096, 256, 0, stream>>>(QKVb, cost, sint, sp, Kr, 2048, 1.0f);
  vtrans<<<dim3(32, 8), 256, 0, stream>>>(QKVb, Vtb);
  attn_kernel<<<dim3(16, 32), 256, 0, stream>>>(Qr, Kr, Vtb, Obuf);
  gemm_bt<false><<<dim3(16, 32), 256, 0, stream>>>(Obuf, Wot, bo, (float*)d_out, 4096, 2048, 2048);
}

// Round 2
// 256.329 us; speedup vs baseline: 1.5455x; 1.5455x over previous
//
#include <hip/hip_runtime.h>

typedef __attribute__((ext_vector_type(8))) short short8;
typedef __attribute__((ext_vector_type(4))) float f32x4;
typedef __attribute__((ext_vector_type(16))) float f32x16;

#define DEVFN __device__ __forceinline__

DEVFN unsigned short f2bf(float f) {
  unsigned int u = __builtin_bit_cast(unsigned int, f);
  u += 0x7FFFu + ((u >> 16) & 1u);   // RNE
  return (unsigned short)(u >> 16);
}
DEVFN float bf2f(unsigned int u) { return __builtin_bit_cast(float, u << 16); }

DEVFN unsigned int cvtpk_bf16(float lo, float hi) {
  unsigned int d;
  asm("v_cvt_pk_bf16_f32 %0, %1, %2" : "=v"(d) : "v"(lo), "v"(hi));
  return d;
}
DEVFN void plswap32(unsigned int& a, unsigned int& b) {
  asm("v_permlane32_swap_b32 %0, %1" : "+v"(a), "+v"(b));
}

// ---------------- prep kernels ----------------

// cos/sin tables: [2048 pos][32 freq]
__global__ __launch_bounds__(256) void mk_tables(float* __restrict__ cost, float* __restrict__ sint) {
  int gid = blockIdx.x * 256 + threadIdx.x;   // 65536
  int pos = gid >> 5, i = gid & 31;
  float theta = powf(10000.0f, -(float)(2 * i) / 64.0f);
  float ang = (float)pos * theta;
  cost[gid] = cosf(ang);
  sint[gid] = sinf(ang);
}

__global__ __launch_bounds__(256) void bias_cat_k(const float* __restrict__ bq, const float* __restrict__ bk,
                                                  const float* __restrict__ bv, float* __restrict__ out) {
  int i = blockIdx.x * 256 + threadIdx.x;  // 3072
  float v;
  if (i < 2048) v = bq[i];
  else if (i < 2560) v = bk[i - 2048];
  else v = bv[i - 2560];
  out[i] = v;
}

__global__ __launch_bounds__(256) void convx(const float* __restrict__ x, unsigned short* __restrict__ xb) {
  int gid = blockIdx.x * 256 + threadIdx.x;   // 1048576 threads, 8 f32 each
  const float4* xv = (const float4*)x;
  float4 a = xv[(size_t)gid * 2], b = xv[(size_t)gid * 2 + 1];
  short8 u;
  u[0] = (short)f2bf(a.x); u[1] = (short)f2bf(a.y); u[2] = (short)f2bf(a.z); u[3] = (short)f2bf(a.w);
  u[4] = (short)f2bf(b.x); u[5] = (short)f2bf(b.y); u[6] = (short)f2bf(b.z); u[7] = (short)f2bf(b.w);
  *(short8*)(xb + (size_t)gid * 8) = u;
}

// W [2048][ncols] f32 -> Wt [ncols][2048] bf16 (Wt pre-offset by caller)
__global__ __launch_bounds__(256) void transw(const float* __restrict__ W, unsigned short* __restrict__ Wt, int ncols) {
  __shared__ float lds[32][33];
  int n0 = blockIdx.x * 32, k0 = blockIdx.y * 32;
  int tx = threadIdx.x & 31, ty = threadIdx.x >> 5;
  #pragma unroll
  for (int i = 0; i < 4; i++) {
    int kr = ty + i * 8;
    lds[kr][tx] = W[(size_t)(k0 + kr) * ncols + n0 + tx];
  }
  __syncthreads();
  #pragma unroll
  for (int i = 0; i < 4; i++) {
    int nr = ty + i * 8;
    Wt[(size_t)(n0 + nr) * 2048 + k0 + tx] = f2bf(lds[tx][nr]);
  }
}

// ---------------- RoPE + scatter ----------------
// QKV bf16 [4096][3072]; dst [B][NH][2048][128] bf16; one thread per (m,h,pair j)
template<int NH>
__global__ __launch_bounds__(256) void rope_scatter(const unsigned short* __restrict__ QKV,
    const float* __restrict__ cost, const float* __restrict__ sint, const int* __restrict__ spp,
    unsigned short* __restrict__ dst, int colOff, float scale) {
  constexpr int LOG2NH = (NH == 16) ? 4 : 2;
  int gid = blockIdx.x * 256 + threadIdx.x;
  int j = gid & 63;
  int h = (gid >> 6) & (NH - 1);
  int m = gid >> (6 + LOG2NH);
  int t = m & 2047;
  const unsigned short* src = QKV + (size_t)m * 3072 + colOff + h * 128 + 2 * j;
  unsigned int pair = *(const unsigned int*)src;
  float xv = bf2f(pair & 0xFFFFu), yv = bf2f(pair >> 16);
  float rx, ry;
  if (j < 32) {
    int pos = (spp[0] + t) & 2047;
    float c = cost[pos * 32 + j], s = sint[pos * 32 + j];
    rx = xv * c - yv * s;
    ry = xv * s + yv * c;
  } else { rx = xv; ry = yv; }
  rx *= scale; ry *= scale;
  size_t drow = ((size_t)((m >> 11) * NH + h)) * 2048 + t;
  unsigned int outp = (unsigned int)f2bf(rx) | ((unsigned int)f2bf(ry) << 16);
  *(unsigned int*)(dst + drow * 128 + 2 * j) = outp;
}

// ---------------- V transpose: QKV[.,2560+kh*128+d] -> Vt[b][kh][d][t] ----------------
__global__ __launch_bounds__(256) void vtrans(const unsigned short* __restrict__ QKV, unsigned short* __restrict__ Vt) {
  __shared__ __align__(16) unsigned short lds[64 * 128];  // swizzled [t][d]
  int tid = threadIdx.x;
  int t0 = blockIdx.x * 64;
  int bk = blockIdx.y;         // b*4 + kh
  const unsigned short* src = QKV + (size_t)(bk >> 2) * 2048 * 3072 + 2560 + (bk & 3) * 128;
  #pragma unroll
  for (int c = 0; c < 4; c++) {
    int idx = c * 256 + tid;
    int tr = idx >> 4, dc = idx & 15;
    short8 v = *(const short8*)(src + (size_t)(t0 + tr) * 3072 + dc * 8);
    *(short8*)((char*)lds + tr * 256 + 16 * (dc ^ (tr >> 3))) = v;
  }
  __syncthreads();
  unsigned short* dstb = Vt + (size_t)bk * 128 * 2048;
  #pragma unroll
  for (int c2 = 0; c2 < 4; c2++) {
    int idx2 = c2 * 256 + tid;
    int tc = idx2 & 7, d = idx2 >> 3;
    short8 u;
    #pragma unroll
    for (int e = 0; e < 8; e++) {
      int t = 8 * tc + e;
      u[e] = *(const short*)((char*)lds + t * 256 + 16 * ((d >> 3) ^ tc) + (d & 7) * 2);
    }
    *(short8*)(dstb + (size_t)d * 2048 + t0 + 8 * tc) = u;
  }
}

// ---------------- GEMM: C[M][N] = A[M][K] * Bt[N][K]^T + bias, m97 structure ----------------
template<bool BF16OUT>
__global__ __launch_bounds__(256, 2) void gemm_bt(
    const unsigned short* __restrict__ A, const unsigned short* __restrict__ Bt,
    const float* __restrict__ bias, void* __restrict__ Cout, int M, int N, int K) {
  __shared__ __align__(16) unsigned short Asl[128 * 64];
  __shared__ __align__(16) unsigned short Bsl[128 * 64];
  int tid = threadIdx.x;
  int lane = tid & 63, w = tid >> 6;
  int wr = w >> 1, wc = w & 1;
  int m0 = blockIdx.y * 128, n0 = blockIdx.x * 128;

  f32x4 acc[4][4];
  #pragma unroll
  for (int i = 0; i < 4; i++)
    #pragma unroll
    for (int j = 0; j < 4; j++)
      #pragma unroll
      for (int r = 0; r < 4; r++) acc[i][j][r] = 0.f;

  int srow = w * 32 + (lane >> 3);
  int kc8 = (lane & 7) * 8;
  const unsigned short* Aptr = A + (size_t)(m0 + srow) * K + kc8;
  const unsigned short* Bptr = Bt + (size_t)(n0 + srow) * K + kc8;
  unsigned short* AslW = Asl + w * 4 * 512;
  unsigned short* BslW = Bsl + w * 4 * 512;

  for (int k0 = 0; k0 < K; k0 += 64) {
    __syncthreads();
    #pragma unroll
    for (int i = 0; i < 4; i++) {
      __builtin_amdgcn_global_load_lds(
        (const __attribute__((address_space(1))) unsigned int*)(Aptr + (size_t)i * 8 * K + k0),
        (__attribute__((address_space(3))) unsigned int*)(AslW + i * 512), 16, 0, 0);
      __builtin_amdgcn_global_load_lds(
        (const __attribute__((address_space(1))) unsigned int*)(Bptr + (size_t)i * 8 * K + k0),
        (__attribute__((address_space(3))) unsigned int*)(BslW + i * 512), 16, 0, 0);
    }
    __syncthreads();
    #pragma unroll
    for (int ks = 0; ks < 2; ks++) {
      short8 af[4], bfr[4];
      #pragma unroll
      for (int mi = 0; mi < 4; mi++)
        af[mi] = *(const short8*)(Asl + (wr * 64 + mi * 16 + (lane & 15)) * 64 + ks * 32 + (lane >> 4) * 8);
      #pragma unroll
      for (int ni = 0; ni < 4; ni++)
        bfr[ni] = *(const short8*)(Bsl + (wc * 64 + ni * 16 + (lane & 15)) * 64 + ks * 32 + (lane >> 4) * 8);
      #pragma unroll
      for (int mi = 0; mi < 4; mi++)
        #pragma unroll
        for (int ni = 0; ni < 4; ni++)
          acc[mi][ni] = __builtin_amdgcn_mfma_f32_16x16x32_bf16(af[mi], bfr[ni], acc[mi][ni], 0, 0, 0);
    }
  }
  int cl = lane & 15, rq = lane >> 4;
  #pragma unroll
  for (int mi = 0; mi < 4; mi++) {
    #pragma unroll
    for (int ni = 0; ni < 4; ni++) {
      int gn = n0 + wc * 64 + ni * 16 + cl;
      float bv = bias[gn];
      #pragma unroll
      for (int r = 0; r < 4; r++) {
        int gm = m0 + wr * 64 + mi * 16 + rq * 4 + r;
        float v = acc[mi][ni][r] + bv;
        if (BF16OUT) ((unsigned short*)Cout)[(size_t)gm * N + gn] = f2bf(v);
        else ((float*)Cout)[(size_t)gm * N + gn] = v;
      }
    }
  }
}

// ---------------- flash attention v2: swapped QK^T, in-register softmax ----------------
// Qr [B][16][T][128] bf16, pre-scaled by (1/sqrt(128))*log2(e); Kr [B][4][T][128]; Vt [B][4][128][T]
// grid: (T/64, B*16); 2 waves, 32 q-rows per wave, KV tile = 64
__global__ __launch_bounds__(128, 2) void attn_kernel(
    const unsigned short* __restrict__ Qr, const unsigned short* __restrict__ Kr,
    const unsigned short* __restrict__ Vt, unsigned short* __restrict__ O) {
  __shared__ __align__(16) unsigned short K_lds[64 * 136];   // [kv][128 + 8 pad]
  __shared__ __align__(16) unsigned short V_lds[128 * 72];   // [d][64 + 8 pad]
  __shared__ float bl_lds[2 * 32];                           // per-wave broadcast (al / inv-l)

  const int tid = threadIdx.x;
  const int lane = tid & 63;
  const int w = tid >> 6;
  const int l31 = lane & 31;
  const int hf = lane >> 5;
  const int q0 = blockIdx.x * 64;
  const int bh = blockIdx.y;
  const int b = bh >> 4, h = bh & 15;
  const int kh = h >> 2;
  const int qw = q0 + w * 32;       // this wave's q base; lane's q = qw + l31

  // Q as B-operand fragments: col=lane&31 = q, k = s*16 + 8*hf + e
  const unsigned short* qbase = Qr + (((size_t)(b * 16 + h)) * 2048 + (qw + l31)) * 128;
  short8 qf[8];
  #pragma unroll
  for (int s = 0; s < 8; s++)
    qf[s] = *(const short8*)(qbase + s * 16 + hf * 8);

  float m_r = -3.0e38f, l_r = 0.f;
  f32x16 oacc[4];
  #pragma unroll
  for (int dt = 0; dt < 4; dt++)
    #pragma unroll
    for (int r = 0; r < 16; r++) oacc[dt][r] = 0.f;

  const unsigned short* kbase = Kr + ((size_t)(b * 4 + kh)) * 2048 * 128;
  const unsigned short* vbase = Vt + ((size_t)(b * 4 + kh)) * 128 * 2048;

  const int ntiles = blockIdx.x + 1;
  for (int kt = 0; kt < ntiles; kt++) {
    const int kv0 = kt * 64;
    __syncthreads();
    #pragma unroll
    for (int c = 0; c < 8; c++) {      // stage K: 64x128 (128 threads)
      int idx = c * 128 + tid;
      int kvr = idx >> 4, dc = idx & 15;
      short8 v = *(const short8*)(kbase + (size_t)(kv0 + kvr) * 128 + dc * 8);
      *(short8*)((char*)K_lds + kvr * 272 + dc * 16) = v;
    }
    #pragma unroll
    for (int c = 0; c < 8; c++) {      // stage V^T: 128x64
      int idx = c * 128 + tid;
      int d = idx >> 3, kvc = idx & 7;
      short8 v = *(const short8*)(vbase + (size_t)d * 2048 + kv0 + kvc * 8);
      *(short8*)((char*)V_lds + d * 144 + kvc * 16) = v;
    }
    __syncthreads();

    // S^T[kv][q] = K · Q^T : two 32x32 tiles (kv halves), A = K rows, B = Q cols
    f32x16 sc[2];
    #pragma unroll
    for (int ct = 0; ct < 2; ct++) {
      #pragma unroll
      for (int r = 0; r < 16; r++) sc[ct][r] = 0.f;
      #pragma unroll
      for (int s = 0; s < 8; s++) {
        short8 kf = *(const short8*)((char*)K_lds + (ct * 32 + l31) * 272 + s * 32 + hf * 16);
        sc[ct] = __builtin_amdgcn_mfma_f32_32x32x16_bf16(kf, qf[s], sc[ct], 0, 0, 0);
      }
    }
    // causal mask (only the diagonal tile needs it): row of C = kv, col = q
    if (kv0 + 63 > qw) {
      #pragma unroll
      for (int ct = 0; ct < 2; ct++)
        #pragma unroll
        for (int r = 0; r < 16; r++) {
          int kg = kv0 + ct * 32 + (r & 3) + 8 * (r >> 2) + 4 * hf;
          if (kg > qw + l31) sc[ct][r] = -3.0e38f;
        }
    }
    // in-register row softmax (lane owns q = qw + l31; 32 kv values in regs, other 32 in lane^32)
    float mx[16];
    #pragma unroll
    for (int r = 0; r < 16; r++) mx[r] = fmaxf(sc[0][r], sc[1][r]);
    #pragma unroll
    for (int s2 = 8; s2 >= 1; s2 >>= 1)
      #pragma unroll
      for (int i = 0; i < 8; i++) if (i < s2) mx[i] = fmaxf(mx[i], mx[i + s2]);
    float tm = fmaxf(mx[0], __shfl_xor(mx[0], 32));
    float mn = fmaxf(m_r, tm);
    float al = __builtin_amdgcn_exp2f(m_r - mn);
    m_r = mn;
    #pragma unroll
    for (int ct = 0; ct < 2; ct++)
      #pragma unroll
      for (int r = 0; r < 16; r++) sc[ct][r] = __builtin_amdgcn_exp2f(sc[ct][r] - mn);
    float sm[16];
    #pragma unroll
    for (int r = 0; r < 16; r++) sm[r] = sc[0][r] + sc[1][r];
    #pragma unroll
    for (int s2 = 8; s2 >= 1; s2 >>= 1)
      #pragma unroll
      for (int i = 0; i < 8; i++) if (i < s2) sm[i] += sm[i + s2];
    float rs = sm[0] + __shfl_xor(sm[0], 32);
    l_r = l_r * al + rs;
    if (lane < 32) bl_lds[w * 32 + l31] = al;

    // repack P -> A-fragments: 16 cvt_pk + 8 permlane32_swap
    short8 pa[4];
    #pragma unroll
    for (int ks = 0; ks < 4; ks++) {
      const int ct = ks >> 1, kb = (ks & 1) * 8;
      unsigned int A0 = cvtpk_bf16(sc[ct][kb + 0], sc[ct][kb + 1]);
      unsigned int A1 = cvtpk_bf16(sc[ct][kb + 2], sc[ct][kb + 3]);
      unsigned int B0 = cvtpk_bf16(sc[ct][kb + 4], sc[ct][kb + 5]);
      unsigned int B1 = cvtpk_bf16(sc[ct][kb + 6], sc[ct][kb + 7]);
      plswap32(A0, B0);
      plswap32(A1, B1);
      union { unsigned int wds[4]; short8 s8; } u;
      u.wds[0] = A0; u.wds[1] = A1; u.wds[2] = B0; u.wds[3] = B1;
      pa[ks] = u.s8;
    }
    // rescale O rows by al (broadcast per-row factor from LDS)
    #pragma unroll
    for (int r = 0; r < 16; r++) {
      float alr = bl_lds[w * 32 + (r & 3) + 8 * (r >> 2) + 4 * hf];
      #pragma unroll
      for (int dt = 0; dt < 4; dt++) oacc[dt][r] *= alr;
    }
    // PV: O[32q x 128d] += P[32x64] * V[64x128]
    #pragma unroll
    for (int dt = 0; dt < 4; dt++) {
      #pragma unroll
      for (int ks = 0; ks < 4; ks++) {
        short8 vf = *(const short8*)((char*)V_lds + (dt * 32 + l31) * 144 + ks * 32 + hf * 16);
        oacc[dt] = __builtin_amdgcn_mfma_f32_32x32x16_bf16(pa[ks], vf, oacc[dt], 0, 0, 0);
      }
    }
  }
  // epilogue: broadcast 1/l per row, write O[b][q][h*128 + d]
  if (lane < 32) bl_lds[w * 32 + l31] = 1.0f / l_r;
  #pragma unroll
  for (int r = 0; r < 16; r++) {
    int rloc = (r & 3) + 8 * (r >> 2) + 4 * hf;
    float inv = bl_lds[w * 32 + rloc];
    int qg = qw + rloc;
    unsigned short* orow = O + ((size_t)(b * 2048 + qg)) * 2048 + h * 128;
    #pragma unroll
    for (int dt = 0; dt < 4; dt++)
      orow[dt * 32 + l31] = f2bf(oacc[dt][r] * inv);
  }
}

// ---------------- launch ----------------
extern "C" void kernel_launch(void* const* d_in, const int* in_sizes, int n_in,
                              void* d_out, int out_size, void* d_ws, size_t ws_size,
                              hipStream_t stream) {
  (void)in_sizes; (void)n_in; (void)out_size; (void)ws_size;
  const float* x  = (const float*)d_in[0];
  const float* Wq = (const float*)d_in[1];
  const float* bq = (const float*)d_in[2];
  const float* Wk = (const float*)d_in[3];
  const float* bk = (const float*)d_in[4];
  const float* Wv = (const float*)d_in[5];
  const float* bv = (const float*)d_in[6];
  const float* Wo = (const float*)d_in[7];
  const float* bo = (const float*)d_in[8];
  const int*   sp = (const int*)d_in[9];

  char* ws = (char*)d_ws;
  unsigned short* xb    = (unsigned short*)ws;                // 16,777,216 B (reused as Obuf)
  unsigned short* Wqkvt = (unsigned short*)(ws + 16777216);   // 12,582,912
  unsigned short* Wot   = (unsigned short*)(ws + 29360128);   //  8,388,608
  unsigned short* QKVb  = (unsigned short*)(ws + 37748736);   // 25,165,824 (bf16 [4096][3072])
  float* cost           = (float*)(ws + 62914560);            //    262,144
  float* sint           = (float*)(ws + 63176704);            //    262,144
  float* bcat           = (float*)(ws + 63438848);            //     12,288

  unsigned short* Obuf = xb;  // xb dead after GEMM1
  unsigned short* Qr = (unsigned short*)d_out;
  unsigned short* Kr = (unsigned short*)((char*)d_out + 16777216);
  unsigned short* Vtb = (unsigned short*)((char*)d_out + 20971520);

  mk_tables<<<256, 256, 0, stream>>>(cost, sint);
  bias_cat_k<<<12, 256, 0, stream>>>(bq, bk, bv, bcat);
  convx<<<4096, 256, 0, stream>>>(x, xb);
  transw<<<dim3(64, 64), 256, 0, stream>>>(Wq, Wqkvt, 2048);
  transw<<<dim3(16, 64), 256, 0, stream>>>(Wk, Wqkvt + (size_t)2048 * 2048, 512);
  transw<<<dim3(16, 64), 256, 0, stream>>>(Wv, Wqkvt + (size_t)2560 * 2048, 512);
  transw<<<dim3(64, 64), 256, 0, stream>>>(Wo, Wot, 2048);
  gemm_bt<true><<<dim3(24, 32), 256, 0, stream>>>(xb, Wqkvt, bcat, QKVb, 4096, 3072, 2048);
  // Q scale = (1/sqrt(128)) * log2(e) so softmax can use exp2 directly
  rope_scatter<16><<<16384, 256, 0, stream>>>(QKVb, cost, sint, sp, Qr, 0, 0.12751743f);
  rope_scatter<4><<<4096, 256, 0, stream>>>(QKVb, cost, sint, sp, Kr, 2048, 1.0f);
  vtrans<<<dim3(32, 8), 256, 0, stream>>>(QKVb, Vtb);
  attn_kernel<<<dim3(32, 32), 128, 0, stream>>>(Qr, Kr, Vtb, Obuf);
  gemm_bt<false><<<dim3(16, 32), 256, 0, stream>>>(Obuf, Wot, bo, (float*)d_out, 4096, 2048, 2048);
}